// Round 1
// baseline (43775.107 us; speedup 1.0000x reference)
//
#include <hip/hip_runtime.h>
#include <hip/hip_bf16.h>
#include <hip/hip_cooperative_groups.h>

namespace cg = cooperative_groups;

#define B_   128
#define TT   1024
#define I_   256
#define H_   512

typedef __bf16 bf16x8 __attribute__((ext_vector_type(8)));
typedef float  f32x4  __attribute__((ext_vector_type(4)));

__device__ __forceinline__ float sigm(float x) { return 1.f / (1.f + __expf(-x)); }
__device__ __forceinline__ float tanh_(float x) {
    float t = __expf(-2.f * fabsf(x));
    float r = (1.f - t) / (1.f + t);
    return copysignf(r, x);
}

// ---------------- prep kernels ----------------

// Pack W1 (ih:K=256 | hh:K=512 -> K=768) into [jt][kg=96][p=64][8] bf16,
// p -> (jj = (p>>4)*4 + ((p&15)>>2), gate = p&3), row = gate*512 + jt*16 + jj
__global__ void pack_w1(const float* __restrict__ Wih, const float* __restrict__ Whh,
                        const float* __restrict__ bih, const float* __restrict__ bhh,
                        __hip_bfloat16* __restrict__ Wp, float* __restrict__ bcp) {
    int idx = blockIdx.x * 256 + threadIdx.x;           // 32*96*64*8 = 1,572,864
    int e = idx & 7, pp = (idx >> 3) & 63;
    int kgjt = idx >> 9;
    int kg = kgjt % 96, jt = kgjt / 96;
    int gate = pp & 3;
    int jjb = ((pp >> 4) << 2) | ((pp & 15) >> 2);
    int row = gate * 512 + jt * 16 + jjb;
    int k = kg * 8 + e;
    float v = (k < 256) ? Wih[row * 256 + k] : Whh[(size_t)row * 512 + (k - 256)];
    Wp[idx] = __float2bfloat16(v);
    if (kg == 0 && e == 0) bcp[jt * 64 + pp] = bih[row] + bhh[row];
}

// Pack W2 (ih:K=512 | hh:K=512 -> K=1024) into [jt][kg=128][p=64][8]
__global__ void pack_w2(const float* __restrict__ Wih, const float* __restrict__ Whh,
                        const float* __restrict__ bih, const float* __restrict__ bhh,
                        __hip_bfloat16* __restrict__ Wp, float* __restrict__ bcp) {
    int idx = blockIdx.x * 256 + threadIdx.x;           // 32*128*64*8 = 2,097,152
    int e = idx & 7, pp = (idx >> 3) & 63;
    int kg = (idx >> 9) & 127, jt = idx >> 16;
    int gate = pp & 3;
    int jjb = ((pp >> 4) << 2) | ((pp & 15) >> 2);
    int row = gate * 512 + jt * 16 + jjb;
    int k = kg * 8 + e;
    float v = (k < 512) ? Wih[(size_t)row * 512 + k] : Whh[(size_t)row * 512 + (k - 512)];
    Wp[idx] = __float2bfloat16(v);
    if (kg == 0 && e == 0) bcp[jt * 64 + pp] = bih[row] + bhh[row];
}

// x [B][T][I] f32 -> xbT [T][B][I] bf16
__global__ void xconv(const float* __restrict__ x, __hip_bfloat16* __restrict__ xbT) {
    long idx = (long)blockIdx.x * 256 + threadIdx.x;    // over T*B*I/4
    long base = idx * 4;
    int i = (int)(base & (I_ - 1));
    int t = (int)((base >> 8) & (TT - 1));
    int b = (int)(base >> 18);
    const float4 v = *(const float4*)(x + ((long)b * TT + t) * I_ + i);
    __hip_bfloat16* o = xbT + ((long)t * B_ + b) * I_ + i;
    o[0] = __float2bfloat16(v.x); o[1] = __float2bfloat16(v.y);
    o[2] = __float2bfloat16(v.z); o[3] = __float2bfloat16(v.w);
}

// ---------------- recurrent phase body ----------------

template <int NKS>
__device__ __forceinline__ void mm_part(const __hip_bfloat16* __restrict__ A, int rowStride,
                                        const bf16x8* __restrict__ wl, int kgBase,
                                        int r, int arow, int kseg, int colc,
                                        f32x4& acc0, f32x4& acc1) {
    const __hip_bfloat16* ap0 = A + (r * 32 + arow) * rowStride + kseg * 8;
    const __hip_bfloat16* ap1 = ap0 + 16 * rowStride;
    bf16x8 a0[NKS], a1[NKS], bb[NKS];
#pragma unroll
    for (int s = 0; s < NKS; ++s) {
        a0[s] = *reinterpret_cast<const bf16x8*>(ap0 + s * 32);
        a1[s] = *reinterpret_cast<const bf16x8*>(ap1 + s * 32);
        bb[s] = wl[(kgBase + s * 4 + kseg) * 64 + colc];
    }
#pragma unroll
    for (int s = 0; s < NKS; ++s) {
        acc0 = __builtin_amdgcn_mfma_f32_16x16x32_bf16(a0[s], bb[s], acc0, 0, 0, 0);
        acc1 = __builtin_amdgcn_mfma_f32_16x16x32_bf16(a1[s], bb[s], acc1, 0, 0, 0);
    }
}

// One pipeline phase p (0..TT). Blocks 0..127: layer1 computes h1[p] (p<TT).
// Blocks 128..255: layer2 computes h2[p-1] (p>=1).
__device__ __forceinline__ void lstm_phase(
    int p, int bid, int tid,
    const __hip_bfloat16* __restrict__ xbT,
    const float* __restrict__ bcp1, const float* __restrict__ bcp2,
    __hip_bfloat16* __restrict__ h1b, __hip_bfloat16* __restrict__ h2b,
    float* __restrict__ cw1, float* __restrict__ cw2,
    const bf16x8* wlds) {
    const int wave = tid >> 6, lane = tid & 63;
    const bool isL2 = bid >= 128;
    const int lb = bid & 127;
    const int r = lb >> 5, jt = lb & 31;
    const bool active = isL2 ? (p >= 1) : (p < TT);
    if (!active) return;

    const __hip_bfloat16* h1r = h1b + ((p - 1) & 1) * (B_ * H_);
    f32x4 acc0 = {0.f, 0.f, 0.f, 0.f};
    f32x4 acc1 = {0.f, 0.f, 0.f, 0.f};
    const int arow = lane & 15;
    const int kseg = lane >> 4;
    const int colc = wave * 16 + arow;

    if (!isL2) {
        const __hip_bfloat16* xb = xbT + (size_t)p * (B_ * I_);
        mm_part<8>(xb, I_, wlds, 0, r, arow, kseg, colc, acc0, acc1);    // x part (K=256)
        mm_part<16>(h1r, H_, wlds, 32, r, arow, kseg, colc, acc0, acc1); // h1 part (K=512)
    } else {
        const __hip_bfloat16* h2r = h2b + (p & 1) * (B_ * H_);           // h2[p-2]
        mm_part<16>(h1r, H_, wlds, 0, r, arow, kseg, colc, acc0, acc1);  // h1[p-1]
        mm_part<16>(h2r, H_, wlds, 64, r, arow, kseg, colc, acc0, acc1); // h2[p-2]
    }

    // epilogue: bias + gates + state update
    const float* bcp = isL2 ? bcp2 : bcp1;
    float bcol = bcp[jt * 64 + wave * 16 + arow];
    float* cw = isL2 ? cw2 : cw1;
    __hip_bfloat16* hout = isL2 ? (h2b + ((p - 1) & 1) * (B_ * H_))
                                : (h1b + (p & 1) * (B_ * H_));
    const int jcol = jt * 16 + wave * 4 + (arow >> 2);
    const int g4 = lane & 3;
#pragma unroll
    for (int fr = 0; fr < 2; ++fr) {
        f32x4 av = fr ? acc1 : acc0;
#pragma unroll
        for (int j = 0; j < 4; ++j) {
            int row = r * 32 + fr * 16 + kseg * 4 + j;
            float v = av[j] + bcol;
            float t1 = __shfl_xor(v, 1);
            float t2 = __shfl_xor(v, 2);
            float t3 = __shfl_xor(v, 3);
            float iv, fv, gv, ov;
            if      (g4 == 0) { iv = v;  fv = t1; gv = t2; ov = t3; }
            else if (g4 == 1) { iv = t1; fv = v;  gv = t3; ov = t2; }
            else if (g4 == 2) { iv = t2; fv = t3; gv = v;  ov = t1; }
            else              { iv = t3; fv = t2; gv = t1; ov = v;  }
            iv = sigm(iv); fv = sigm(fv); gv = tanh_(gv); ov = sigm(ov);
            float cold = cw[row * 512 + jcol];
            float cn = fv * cold + iv * gv;
            float hn = ov * tanh_(cn);
            if (g4 == 0) {
                cw[row * 512 + jcol] = cn;
                hout[row * 512 + jcol] = __float2bfloat16(hn);
            }
        }
    }
}

__device__ __forceinline__ void load_weights_lds(int bid, int tid, bf16x8* wlds,
                                                 const __hip_bfloat16* W1p,
                                                 const __hip_bfloat16* W2p) {
    const bool isL2 = bid >= 128;
    const int jt = bid & 31;
    const bf16x8* wsrc = reinterpret_cast<const bf16x8*>(isL2 ? W2p : W1p) +
                         (size_t)jt * (isL2 ? 128 * 64 : 96 * 64);
    const int nchunk = isL2 ? 8192 : 6144;
    for (int c = tid; c < nchunk; c += 256) wlds[c] = wsrc[c];
}

__global__ void __launch_bounds__(256, 1) lstm_coop(
    const __hip_bfloat16* __restrict__ xbT,
    const __hip_bfloat16* __restrict__ W1p, const __hip_bfloat16* __restrict__ W2p,
    const float* __restrict__ bcp1, const float* __restrict__ bcp2,
    __hip_bfloat16* __restrict__ h1b, __hip_bfloat16* __restrict__ h2b,
    float* __restrict__ cw1, float* __restrict__ cw2) {
    __shared__ bf16x8 wlds[8192];   // 128 KB
    const int bid = blockIdx.x, tid = threadIdx.x;
    load_weights_lds(bid, tid, wlds, W1p, W2p);
    __syncthreads();
    cg::grid_group g = cg::this_grid();
    g.sync();
    for (int p = 0; p <= TT; ++p) {
        lstm_phase(p, bid, tid, xbT, bcp1, bcp2, h1b, h2b, cw1, cw2, wlds);
        g.sync();
    }
}

// fallback: one launch per phase (kernel boundary = the sync)
__global__ void __launch_bounds__(256, 1) lstm_step(
    int p,
    const __hip_bfloat16* __restrict__ xbT,
    const __hip_bfloat16* __restrict__ W1p, const __hip_bfloat16* __restrict__ W2p,
    const float* __restrict__ bcp1, const float* __restrict__ bcp2,
    __hip_bfloat16* __restrict__ h1b, __hip_bfloat16* __restrict__ h2b,
    float* __restrict__ cw1, float* __restrict__ cw2) {
    __shared__ bf16x8 wlds[8192];
    const int bid = blockIdx.x, tid = threadIdx.x;
    load_weights_lds(bid, tid, wlds, W1p, W2p);
    __syncthreads();
    lstm_phase(p, bid, tid, xbT, bcp1, bcp2, h1b, h2b, cw1, cw2, wlds);
}

// out[b][c] = h2[b] . Wout[c] + bout[c]
__global__ void proj_kernel(const __hip_bfloat16* __restrict__ h2,
                            const float* __restrict__ Wout, const float* __restrict__ bout,
                            float* __restrict__ out) {
    int b = blockIdx.x, lane = threadIdx.x; // 64 threads
    const bf16x8 h8 = *reinterpret_cast<const bf16x8*>(h2 + b * 512 + lane * 8);
    float hv[8];
#pragma unroll
    for (int e = 0; e < 8; ++e) hv[e] = (float)h8[e];
    for (int c = 0; c < 10; ++c) {
        const float4 w0 = *(const float4*)(Wout + c * 512 + lane * 8);
        const float4 w1 = *(const float4*)(Wout + c * 512 + lane * 8 + 4);
        float s = hv[0] * w0.x + hv[1] * w0.y + hv[2] * w0.z + hv[3] * w0.w +
                  hv[4] * w1.x + hv[5] * w1.y + hv[6] * w1.z + hv[7] * w1.w;
#pragma unroll
        for (int off = 32; off > 0; off >>= 1) s += __shfl_down(s, off);
        if (lane == 0) out[b * 10 + c] = s + bout[c];
    }
}

extern "C" void kernel_launch(void* const* d_in, const int* in_sizes, int n_in,
                              void* d_out, int out_size, void* d_ws, size_t ws_size,
                              hipStream_t stream) {
    const float* x    = (const float*)d_in[0];
    const float* Wih1 = (const float*)d_in[1];
    const float* Whh1 = (const float*)d_in[2];
    const float* bih1 = (const float*)d_in[3];
    const float* bhh1 = (const float*)d_in[4];
    const float* Wih2 = (const float*)d_in[5];
    const float* Whh2 = (const float*)d_in[6];
    const float* bih2 = (const float*)d_in[7];
    const float* bhh2 = (const float*)d_in[8];
    const float* Wout = (const float*)d_in[9];
    const float* bout = (const float*)d_in[10];
    float* out = (float*)d_out;

    char* ws = (char*)d_ws;
    size_t off = 0;
    auto alloc = [&](size_t bytes) -> void* {
        void* pp = ws + off;
        off += (bytes + 255) & ~(size_t)255;
        return pp;
    };
    __hip_bfloat16* W1p = (__hip_bfloat16*)alloc((size_t)32 * 96 * 64 * 8 * 2);   // 3 MB
    __hip_bfloat16* W2p = (__hip_bfloat16*)alloc((size_t)32 * 128 * 64 * 8 * 2);  // 4 MB
    float* bcp1 = (float*)alloc(2048 * 4);
    float* bcp2 = (float*)alloc(2048 * 4);
    __hip_bfloat16* h1b = (__hip_bfloat16*)alloc((size_t)2 * B_ * H_ * 2);        // 256 KB
    __hip_bfloat16* h2b = (__hip_bfloat16*)alloc((size_t)2 * B_ * H_ * 2);
    float* cw1 = (float*)alloc((size_t)B_ * H_ * 4);
    float* cw2 = (float*)alloc((size_t)B_ * H_ * 4);
    __hip_bfloat16* xbT = (__hip_bfloat16*)alloc((size_t)TT * B_ * I_ * 2);       // 64 MB
    if (off > ws_size) return;  // workspace too small; cannot proceed safely

    // zero h double-buffers + c state (contiguous 1 MB region)
    hipMemsetAsync(h1b, 0, (size_t)2 * 262144 + (size_t)2 * 262144, stream);

    pack_w1<<<(32 * 96 * 64 * 8) / 256, 256, 0, stream>>>(Wih1, Whh1, bih1, bhh1, W1p, bcp1);
    pack_w2<<<(32 * 128 * 64 * 8) / 256, 256, 0, stream>>>(Wih2, Whh2, bih2, bhh2, W2p, bcp2);
    xconv<<<((long)TT * B_ * I_ / 4) / 256, 256, 0, stream>>>(x, xbT);

    // decide cooperative vs per-step fallback
    int dev = 0;
    hipGetDevice(&dev);
    int nCU = 0;
    hipDeviceGetAttribute(&nCU, hipDeviceAttributeMultiprocessorCount, dev);
    int perCU = 0;
    hipOccupancyMaxActiveBlocksPerMultiprocessor(&perCU, lstm_coop, 256, 0);

    const __hip_bfloat16* xbT_ = xbT;
    const __hip_bfloat16* W1p_ = W1p;
    const __hip_bfloat16* W2p_ = W2p;
    const float* bcp1_ = bcp1;
    const float* bcp2_ = bcp2;
    __hip_bfloat16* h1b_ = h1b;
    __hip_bfloat16* h2b_ = h2b;
    float* cw1_ = cw1;
    float* cw2_ = cw2;

    if ((long)perCU * nCU >= 256) {
        void* args[] = {&xbT_, &W1p_, &W2p_, &bcp1_, &bcp2_, &h1b_, &h2b_, &cw1_, &cw2_};
        hipLaunchCooperativeKernel((void*)lstm_coop, dim3(256), dim3(256), args, 0, stream);
    } else {
        for (int p = 0; p <= TT; ++p)
            lstm_step<<<256, 256, 0, stream>>>(p, xbT, W1p, W2p, bcp1, bcp2, h1b, h2b, cw1, cw2);
    }

    // h2[T-1] lives in buffer (T-1)&1 == 1
    proj_kernel<<<B_, 64, 0, stream>>>(h2b + B_ * H_, Wout, bout, out);
}

// Round 3
// 9409.089 us; speedup vs baseline: 4.6524x; 4.6524x over previous
//
#include <hip/hip_runtime.h>
#include <hip/hip_bf16.h>
#include <hip/hip_cooperative_groups.h>

namespace cg = cooperative_groups;

#define B_ 128
#define TT 1024
#define I_ 256
#define H_ 512
#define BH (B_*H_)

typedef __bf16 bf16x8 __attribute__((ext_vector_type(8)));
typedef float  f32x4  __attribute__((ext_vector_type(4)));
typedef unsigned int u32;

__device__ __forceinline__ float sigm(float x){ return 1.f/(1.f+__expf(-x)); }
__device__ __forceinline__ float tanh_(float x){
    float t=__expf(-2.f*fabsf(x)); float r=(1.f-t)/(1.f+t); return copysignf(r,x);
}
__device__ __forceinline__ unsigned bf16bits(float f){
    unsigned x=__float_as_uint(f);
    return (x + 0x7fffu + ((x>>16)&1u)) >> 16;
}

// ---------------- prep kernels ----------------
// Packed layout (per layer): [pbt][ks][ksub=4][row=16][e=8] bf16.
// p_global = pbt*16 + row, p = j*4 + gate (gate fastest) -> W row = gate*512 + j.
// k = ks*32 + ksub*8 + e. L1: NK=24 (k<256 -> x, else h1). L2: NK=32 (k<512 -> h1, else h2).

__global__ void pack_w1(const float* __restrict__ Wih, const float* __restrict__ Whh,
                        const float* __restrict__ bih, const float* __restrict__ bhh,
                        __hip_bfloat16* __restrict__ Wp, float* __restrict__ bcp) {
    int idx = blockIdx.x*256 + threadIdx.x;       // 128*24*512
    int low = idx & 511;
    int e = low & 7, row = (low>>3)&15, ksub = low>>7;
    int rest = idx >> 9;
    int ks = rest % 24, pbt = rest / 24;
    int p = pbt*16 + row;
    int g = p & 3, j = p >> 2;
    int wrow = g*512 + j;
    int k = ks*32 + ksub*8 + e;
    float v = (k < 256) ? Wih[wrow*256 + k] : Whh[(size_t)wrow*512 + (k-256)];
    Wp[idx] = __float2bfloat16(v);
    if (ks==0 && ksub==0 && e==0) bcp[p] = bih[wrow] + bhh[wrow];
}

__global__ void pack_w2(const float* __restrict__ Wih, const float* __restrict__ Whh,
                        const float* __restrict__ bih, const float* __restrict__ bhh,
                        __hip_bfloat16* __restrict__ Wp, float* __restrict__ bcp) {
    int idx = blockIdx.x*256 + threadIdx.x;       // 128*32*512
    int low = idx & 511;
    int e = low & 7, row = (low>>3)&15, ksub = low>>7;
    int rest = idx >> 9;
    int ks = rest & 31, pbt = rest >> 5;
    int p = pbt*16 + row;
    int g = p & 3, j = p >> 2;
    int wrow = g*512 + j;
    int k = ks*32 + ksub*8 + e;
    float v = (k < 512) ? Wih[(size_t)wrow*512 + k] : Whh[(size_t)wrow*512 + (k-512)];
    Wp[idx] = __float2bfloat16(v);
    if (ks==0 && ksub==0 && e==0) bcp[p] = bih[wrow] + bhh[wrow];
}

// x [B][T][I] f32 -> xbT [T][B][I] bf16
__global__ void xconv(const float* __restrict__ x, __hip_bfloat16* __restrict__ xbT) {
    long idx = (long)blockIdx.x * 256 + threadIdx.x;
    long base = idx * 4;
    int i = (int)(base & (I_ - 1));
    int t = (int)((base >> 8) & (TT - 1));
    int b = (int)(base >> 18);
    const float4 v = *(const float4*)(x + ((long)b * TT + t) * I_ + i);
    __hip_bfloat16* o = xbT + ((long)t * B_ + b) * I_ + i;
    o[0] = __float2bfloat16(v.x); o[1] = __float2bfloat16(v.y);
    o[2] = __float2bfloat16(v.z); o[3] = __float2bfloat16(v.w);
}

// ---------------- shared epilogue ----------------
// acc regs = gates (i,f,g,o) of one (j=jg, batch=bg). Pairs lanes q<->q^1 to
// form a u32 (2x bf16) store at even jg. Store is relaxed-agent (write-through).
__device__ __forceinline__ void epi_store(const f32x4& acc, const f32x4& bias, float& c,
                                          int jg, int bg, __hip_bfloat16* hout) {
    float iv = sigm(acc[0] + bias[0]);
    float fv = sigm(acc[1] + bias[1]);
    float gv = tanh_(acc[2] + bias[2]);
    float ov = sigm(acc[3] + bias[3]);
    c = fv*c + iv*gv;
    float hv = ov * tanh_(c);
    unsigned hb = bf16bits(hv);
    unsigned pr = (unsigned)__shfl_xor((int)hb, 16);
    if ((jg & 1) == 0) {
        u32 val = hb | (pr << 16);
        __hip_atomic_store((u32*)(hout + (size_t)bg*H_ + jg), val,
                           __ATOMIC_RELAXED, __HIP_MEMORY_SCOPE_AGENT);
    }
}

// ---------------- cooperative persistent kernel ----------------
// 256 blocks x 256 threads. bid = layer*128 + pt*4 + bt.
// Phase p: L1 blocks compute h1[p] (p<TT), L2 blocks compute h2[p-1] (p>=1).
// One cg::grid sync per phase. Weights + c state fully register-resident.

__global__ void __launch_bounds__(256, 1) lstm_coop(
    const __hip_bfloat16* __restrict__ xbT,
    const __hip_bfloat16* __restrict__ W1p, const __hip_bfloat16* __restrict__ W2p,
    const float* __restrict__ bcp1, const float* __restrict__ bcp2,
    __hip_bfloat16* __restrict__ h1b, __hip_bfloat16* __restrict__ h2b)
{
    const int bid = blockIdx.x, tid = threadIdx.x;
    const int lane = tid & 63, w = tid >> 6;
    const int layer = bid >> 7;
    const int r = bid & 127;
    const int pt = r >> 2, bt = r & 3;
    const int q = lane >> 4, col = lane & 15;
    const int bhalf = w >> 1, ppair = w & 1;
    const int bg = bt*32 + bhalf*16 + col;
    const int jg0 = pt*16 + ppair*8 + q;
    const int jg1 = jg0 + 4;
    cg::grid_group g = cg::this_grid();

    if (layer == 0) {
        bf16x8 wr[48];                                   // [a=2][ks=24], 192 VGPRs
        const bf16x8* Wg = reinterpret_cast<const bf16x8*>(W1p);
#pragma unroll
        for (int a = 0; a < 2; ++a) {
            int pbt = pt*4 + ppair*2 + a;
#pragma unroll
            for (int ks = 0; ks < 24; ++ks)
                wr[a*24 + ks] = Wg[(pbt*24 + ks)*64 + q*16 + col];
        }
        const f32x4 bias0 = *reinterpret_cast<const f32x4*>(bcp1 + jg0*4);
        const f32x4 bias1 = *reinterpret_cast<const f32x4*>(bcp1 + jg1*4);
        float c0 = 0.f, c1 = 0.f;
        bf16x8 xc[8];
        {
            const __hip_bfloat16* xr = xbT + (size_t)bg*I_ + q*8;
#pragma unroll
            for (int s = 0; s < 8; ++s) xc[s] = *reinterpret_cast<const bf16x8*>(xr + s*32);
        }

        for (int p = 0; p <= TT; ++p) {
            if (p < TT) {
                const __hip_bfloat16* h1r = h1b + ((p-1)&1)*BH + (size_t)bg*H_ + q*8;
                f32x4 acc0 = {0.f,0.f,0.f,0.f}, acc1 = {0.f,0.f,0.f,0.f};
#pragma unroll
                for (int s = 0; s < 8; ++s) {
                    acc0 = __builtin_amdgcn_mfma_f32_16x16x32_bf16(wr[s],    xc[s], acc0, 0,0,0);
                    acc1 = __builtin_amdgcn_mfma_f32_16x16x32_bf16(wr[24+s], xc[s], acc1, 0,0,0);
                }
#pragma unroll
                for (int kc = 0; kc < 2; ++kc) {
                    bf16x8 bfr[8];
#pragma unroll
                    for (int s = 0; s < 8; ++s)
                        bfr[s] = *reinterpret_cast<const bf16x8*>(h1r + (kc*8+s)*32);
#pragma unroll
                    for (int s = 0; s < 8; ++s) {
                        acc0 = __builtin_amdgcn_mfma_f32_16x16x32_bf16(wr[8+kc*8+s],  bfr[s], acc0, 0,0,0);
                        acc1 = __builtin_amdgcn_mfma_f32_16x16x32_bf16(wr[32+kc*8+s], bfr[s], acc1, 0,0,0);
                    }
                }
                // prefetch x for p+1 (xc dead after MFMAs; latency hidden by epilogue+sync)
                if (p + 1 < TT) {
                    const __hip_bfloat16* xr2 = xbT + ((size_t)(p+1)*B_ + bg)*I_ + q*8;
#pragma unroll
                    for (int s = 0; s < 8; ++s) xc[s] = *reinterpret_cast<const bf16x8*>(xr2 + s*32);
                }
                __hip_bfloat16* hout = h1b + (p&1)*BH;
                epi_store(acc0, bias0, c0, jg0, bg, hout);
                epi_store(acc1, bias1, c1, jg1, bg, hout);
            }
            g.sync();
        }
    } else {
        bf16x8 wr[64];                                   // [a=2][ks=32], 256 VGPRs
        const bf16x8* Wg = reinterpret_cast<const bf16x8*>(W2p);
#pragma unroll
        for (int a = 0; a < 2; ++a) {
            int pbt = pt*4 + ppair*2 + a;
#pragma unroll
            for (int ks = 0; ks < 32; ++ks)
                wr[a*32 + ks] = Wg[(pbt*32 + ks)*64 + q*16 + col];
        }
        const f32x4 bias0 = *reinterpret_cast<const f32x4*>(bcp2 + jg0*4);
        const f32x4 bias1 = *reinterpret_cast<const f32x4*>(bcp2 + jg1*4);
        float c0 = 0.f, c1 = 0.f;

        for (int p = 0; p <= TT; ++p) {
            if (p >= 1) {
                const __hip_bfloat16* h1r = h1b + ((p-1)&1)*BH + (size_t)bg*H_ + q*8;
                const __hip_bfloat16* h2r = h2b + (p&1)*BH     + (size_t)bg*H_ + q*8;
                f32x4 acc0 = {0.f,0.f,0.f,0.f}, acc1 = {0.f,0.f,0.f,0.f};
#pragma unroll
                for (int kc = 0; kc < 2; ++kc) {
                    bf16x8 bfr[8];
#pragma unroll
                    for (int s = 0; s < 8; ++s)
                        bfr[s] = *reinterpret_cast<const bf16x8*>(h1r + (kc*8+s)*32);
#pragma unroll
                    for (int s = 0; s < 8; ++s) {
                        acc0 = __builtin_amdgcn_mfma_f32_16x16x32_bf16(wr[kc*8+s],    bfr[s], acc0, 0,0,0);
                        acc1 = __builtin_amdgcn_mfma_f32_16x16x32_bf16(wr[32+kc*8+s], bfr[s], acc1, 0,0,0);
                    }
                }
#pragma unroll
                for (int kc = 0; kc < 2; ++kc) {
                    bf16x8 bfr[8];
#pragma unroll
                    for (int s = 0; s < 8; ++s)
                        bfr[s] = *reinterpret_cast<const bf16x8*>(h2r + (kc*8+s)*32);
#pragma unroll
                    for (int s = 0; s < 8; ++s) {
                        acc0 = __builtin_amdgcn_mfma_f32_16x16x32_bf16(wr[16+kc*8+s], bfr[s], acc0, 0,0,0);
                        acc1 = __builtin_amdgcn_mfma_f32_16x16x32_bf16(wr[48+kc*8+s], bfr[s], acc1, 0,0,0);
                    }
                }
                __hip_bfloat16* hout = h2b + ((p-1)&1)*BH;
                epi_store(acc0, bias0, c0, jg0, bg, hout);
                epi_store(acc1, bias1, c1, jg1, bg, hout);
            }
            g.sync();
        }
    }
}

// ---------------- per-phase fallback (c carried in GLOBAL memory) ----------------
__global__ void __launch_bounds__(256, 1) lstm_step(
    int p,
    const __hip_bfloat16* __restrict__ xbT,
    const __hip_bfloat16* __restrict__ W1p, const __hip_bfloat16* __restrict__ W2p,
    const float* __restrict__ bcp1, const float* __restrict__ bcp2,
    __hip_bfloat16* __restrict__ h1b, __hip_bfloat16* __restrict__ h2b,
    float* __restrict__ cw1, float* __restrict__ cw2)
{
    const int bid = blockIdx.x, tid = threadIdx.x;
    const int lane = tid & 63, w = tid >> 6;
    const int layer = bid >> 7;
    const int r = bid & 127;
    const int pt = r >> 2, bt = r & 3;
    const int q = lane >> 4, col = lane & 15;
    const int bhalf = w >> 1, ppair = w & 1;
    const int bg = bt*32 + bhalf*16 + col;
    const int jg0 = pt*16 + ppair*8 + q;
    const int jg1 = jg0 + 4;

    if (layer == 0) {
        if (p >= TT) return;
        bf16x8 wr[48];
        const bf16x8* Wg = reinterpret_cast<const bf16x8*>(W1p);
#pragma unroll
        for (int a = 0; a < 2; ++a) {
            int pbt = pt*4 + ppair*2 + a;
#pragma unroll
            for (int ks = 0; ks < 24; ++ks)
                wr[a*24 + ks] = Wg[(pbt*24 + ks)*64 + q*16 + col];
        }
        const f32x4 bias0 = *reinterpret_cast<const f32x4*>(bcp1 + jg0*4);
        const f32x4 bias1 = *reinterpret_cast<const f32x4*>(bcp1 + jg1*4);
        float c0 = cw1[(size_t)bg*H_ + jg0];
        float c1 = cw1[(size_t)bg*H_ + jg1];
        const __hip_bfloat16* xr = xbT + ((size_t)p*B_ + bg)*I_ + q*8;
        const __hip_bfloat16* h1r = h1b + ((p-1)&1)*BH + (size_t)bg*H_ + q*8;
        f32x4 acc0 = {0.f,0.f,0.f,0.f}, acc1 = {0.f,0.f,0.f,0.f};
#pragma unroll
        for (int s = 0; s < 8; ++s) {
            bf16x8 xv = *reinterpret_cast<const bf16x8*>(xr + s*32);
            acc0 = __builtin_amdgcn_mfma_f32_16x16x32_bf16(wr[s],    xv, acc0, 0,0,0);
            acc1 = __builtin_amdgcn_mfma_f32_16x16x32_bf16(wr[24+s], xv, acc1, 0,0,0);
        }
#pragma unroll
        for (int kc = 0; kc < 2; ++kc) {
#pragma unroll
            for (int s = 0; s < 8; ++s) {
                bf16x8 bv = *reinterpret_cast<const bf16x8*>(h1r + (kc*8+s)*32);
                acc0 = __builtin_amdgcn_mfma_f32_16x16x32_bf16(wr[8+kc*8+s],  bv, acc0, 0,0,0);
                acc1 = __builtin_amdgcn_mfma_f32_16x16x32_bf16(wr[32+kc*8+s], bv, acc1, 0,0,0);
            }
        }
        __hip_bfloat16* hout = h1b + (p&1)*BH;
        epi_store(acc0, bias0, c0, jg0, bg, hout);
        epi_store(acc1, bias1, c1, jg1, bg, hout);
        cw1[(size_t)bg*H_ + jg0] = c0;
        cw1[(size_t)bg*H_ + jg1] = c1;
    } else {
        if (p < 1) return;
        bf16x8 wr[64];
        const bf16x8* Wg = reinterpret_cast<const bf16x8*>(W2p);
#pragma unroll
        for (int a = 0; a < 2; ++a) {
            int pbt = pt*4 + ppair*2 + a;
#pragma unroll
            for (int ks = 0; ks < 32; ++ks)
                wr[a*32 + ks] = Wg[(pbt*32 + ks)*64 + q*16 + col];
        }
        const f32x4 bias0 = *reinterpret_cast<const f32x4*>(bcp2 + jg0*4);
        const f32x4 bias1 = *reinterpret_cast<const f32x4*>(bcp2 + jg1*4);
        float c0 = cw2[(size_t)bg*H_ + jg0];
        float c1 = cw2[(size_t)bg*H_ + jg1];
        const __hip_bfloat16* h1r = h1b + ((p-1)&1)*BH + (size_t)bg*H_ + q*8;
        const __hip_bfloat16* h2r = h2b + (p&1)*BH     + (size_t)bg*H_ + q*8;
        f32x4 acc0 = {0.f,0.f,0.f,0.f}, acc1 = {0.f,0.f,0.f,0.f};
#pragma unroll
        for (int kc = 0; kc < 2; ++kc) {
#pragma unroll
            for (int s = 0; s < 8; ++s) {
                bf16x8 bv = *reinterpret_cast<const bf16x8*>(h1r + (kc*8+s)*32);
                acc0 = __builtin_amdgcn_mfma_f32_16x16x32_bf16(wr[kc*8+s],    bv, acc0, 0,0,0);
                acc1 = __builtin_amdgcn_mfma_f32_16x16x32_bf16(wr[32+kc*8+s], bv, acc1, 0,0,0);
            }
        }
#pragma unroll
        for (int kc = 0; kc < 2; ++kc) {
#pragma unroll
            for (int s = 0; s < 8; ++s) {
                bf16x8 bv = *reinterpret_cast<const bf16x8*>(h2r + (kc*8+s)*32);
                acc0 = __builtin_amdgcn_mfma_f32_16x16x32_bf16(wr[16+kc*8+s], bv, acc0, 0,0,0);
                acc1 = __builtin_amdgcn_mfma_f32_16x16x32_bf16(wr[48+kc*8+s], bv, acc1, 0,0,0);
            }
        }
        __hip_bfloat16* hout = h2b + ((p-1)&1)*BH;
        epi_store(acc0, bias0, c0, jg0, bg, hout);
        epi_store(acc1, bias1, c1, jg1, bg, hout);
        cw2[(size_t)bg*H_ + jg0] = c0;
        cw2[(size_t)bg*H_ + jg1] = c1;
    }
}

// out[b][c] = h2[b] . Wout[c] + bout[c]
__global__ void proj_kernel(const __hip_bfloat16* __restrict__ h2,
                            const float* __restrict__ Wout, const float* __restrict__ bout,
                            float* __restrict__ out) {
    int b = blockIdx.x, lane = threadIdx.x; // 64 threads
    const bf16x8 h8 = *reinterpret_cast<const bf16x8*>(h2 + b * 512 + lane * 8);
    float hv[8];
#pragma unroll
    for (int e = 0; e < 8; ++e) hv[e] = (float)h8[e];
    for (int c = 0; c < 10; ++c) {
        const float4 w0 = *(const float4*)(Wout + c * 512 + lane * 8);
        const float4 w1 = *(const float4*)(Wout + c * 512 + lane * 8 + 4);
        float s = hv[0] * w0.x + hv[1] * w0.y + hv[2] * w0.z + hv[3] * w0.w +
                  hv[4] * w1.x + hv[5] * w1.y + hv[6] * w1.z + hv[7] * w1.w;
#pragma unroll
        for (int off = 32; off > 0; off >>= 1) s += __shfl_down(s, off);
        if (lane == 0) out[b * 10 + c] = s + bout[c];
    }
}

extern "C" void kernel_launch(void* const* d_in, const int* in_sizes, int n_in,
                              void* d_out, int out_size, void* d_ws, size_t ws_size,
                              hipStream_t stream) {
    const float* x    = (const float*)d_in[0];
    const float* Wih1 = (const float*)d_in[1];
    const float* Whh1 = (const float*)d_in[2];
    const float* bih1 = (const float*)d_in[3];
    const float* bhh1 = (const float*)d_in[4];
    const float* Wih2 = (const float*)d_in[5];
    const float* Whh2 = (const float*)d_in[6];
    const float* bih2 = (const float*)d_in[7];
    const float* bhh2 = (const float*)d_in[8];
    const float* Wout = (const float*)d_in[9];
    const float* bout = (const float*)d_in[10];
    float* out = (float*)d_out;

    char* ws = (char*)d_ws;
    size_t off = 0;
    auto alloc = [&](size_t bytes) -> void* {
        void* pp = ws + off;
        off += (bytes + 255) & ~(size_t)255;
        return pp;
    };
    __hip_bfloat16* W1p = (__hip_bfloat16*)alloc((size_t)128*24*512*2);
    __hip_bfloat16* W2p = (__hip_bfloat16*)alloc((size_t)128*32*512*2);
    float* bcp1 = (float*)alloc(2048*4);
    float* bcp2 = (float*)alloc(2048*4);
    __hip_bfloat16* h1b = (__hip_bfloat16*)alloc((size_t)2*BH*2);   // 256 KB
    __hip_bfloat16* h2b = (__hip_bfloat16*)alloc((size_t)2*BH*2);   // 256 KB
    float* cw1 = (float*)alloc((size_t)BH*4);                       // 256 KB (fallback only)
    float* cw2 = (float*)alloc((size_t)BH*4);                       // 256 KB (fallback only)
    __hip_bfloat16* xbT = (__hip_bfloat16*)alloc((size_t)TT*B_*I_*2); // 64 MB
    if (off > ws_size) return;

    // zero h double-buffers + c state (contiguous 1 MB region starting at h1b)
    hipMemsetAsync(h1b, 0, (size_t)4*BH*2 + (size_t)2*BH*4, stream);

    pack_w1<<<(128*24*512)/256, 256, 0, stream>>>(Wih1, Whh1, bih1, bhh1, W1p, bcp1);
    pack_w2<<<(128*32*512)/256, 256, 0, stream>>>(Wih2, Whh2, bih2, bhh2, W2p, bcp2);
    xconv<<<((long)TT*B_*I_/4)/256, 256, 0, stream>>>(x, xbT);

    int dev = 0;
    hipGetDevice(&dev);
    int nCU = 0;
    hipDeviceGetAttribute(&nCU, hipDeviceAttributeMultiprocessorCount, dev);
    int perCU = 0;
    hipOccupancyMaxActiveBlocksPerMultiprocessor(&perCU, lstm_coop, 256, 0);

    const __hip_bfloat16* xbT_ = xbT;
    const __hip_bfloat16* W1p_ = W1p;
    const __hip_bfloat16* W2p_ = W2p;
    const float* bcp1_ = bcp1;
    const float* bcp2_ = bcp2;
    __hip_bfloat16* h1b_ = h1b;
    __hip_bfloat16* h2b_ = h2b;

    if ((long)perCU * nCU >= 256) {
        void* args[] = {&xbT_, &W1p_, &W2p_, &bcp1_, &bcp2_, &h1b_, &h2b_};
        hipLaunchCooperativeKernel((void*)lstm_coop, dim3(256), dim3(256), args, 0, stream);
    } else {
        for (int p = 0; p <= TT; ++p)
            lstm_step<<<256, 256, 0, stream>>>(p, xbT, W1p, W2p, bcp1, bcp2,
                                               h1b, h2b, cw1, cw2);
    }

    // h2[TT-1] is in buffer (TT-1)&1 == 1
    proj_kernel<<<B_, 64, 0, stream>>>(h2b + BH, Wout, bout, out);
}

// Round 4
// 9320.900 us; speedup vs baseline: 4.6964x; 1.0095x over previous
//
#include <hip/hip_runtime.h>
#include <hip/hip_bf16.h>

#define B_ 128
#define TT 1024
#define I_ 256
#define H_ 512
#define BH (B_*H_)

typedef __bf16 bf16x8 __attribute__((ext_vector_type(8)));
typedef float  f32x4  __attribute__((ext_vector_type(4)));
typedef unsigned int u32;

__device__ __forceinline__ float sigm(float x){ return 1.f/(1.f+__expf(-x)); }
__device__ __forceinline__ float tanh_(float x){
    float t=__expf(-2.f*fabsf(x)); float r=(1.f-t)/(1.f+t); return copysignf(r,x);
}
__device__ __forceinline__ unsigned bf16bits(float f){
    unsigned x=__float_as_uint(f);
    return (x + 0x7fffu + ((x>>16)&1u)) >> 16;
}

// ---------------- prep kernels (unchanged, verified R3) ----------------
// Packed layout (per layer): [pbt][ks][ksub=4][row=16][e=8] bf16.
// p_global = pbt*16 + row, p = j*4 + gate (gate fastest) -> W row = gate*512 + j.
// k = ks*32 + ksub*8 + e. L1: NK=24 (k<256 -> x, else h1). L2: NK=32 (k<512 -> h1, else h2).

__global__ void pack_w1(const float* __restrict__ Wih, const float* __restrict__ Whh,
                        const float* __restrict__ bih, const float* __restrict__ bhh,
                        __hip_bfloat16* __restrict__ Wp, float* __restrict__ bcp) {
    int idx = blockIdx.x*256 + threadIdx.x;       // 128*24*512
    int low = idx & 511;
    int e = low & 7, row = (low>>3)&15, ksub = low>>7;
    int rest = idx >> 9;
    int ks = rest % 24, pbt = rest / 24;
    int p = pbt*16 + row;
    int g = p & 3, j = p >> 2;
    int wrow = g*512 + j;
    int k = ks*32 + ksub*8 + e;
    float v = (k < 256) ? Wih[wrow*256 + k] : Whh[(size_t)wrow*512 + (k-256)];
    Wp[idx] = __float2bfloat16(v);
    if (ks==0 && ksub==0 && e==0) bcp[p] = bih[wrow] + bhh[wrow];
}

__global__ void pack_w2(const float* __restrict__ Wih, const float* __restrict__ Whh,
                        const float* __restrict__ bih, const float* __restrict__ bhh,
                        __hip_bfloat16* __restrict__ Wp, float* __restrict__ bcp) {
    int idx = blockIdx.x*256 + threadIdx.x;       // 128*32*512
    int low = idx & 511;
    int e = low & 7, row = (low>>3)&15, ksub = low>>7;
    int rest = idx >> 9;
    int ks = rest & 31, pbt = rest >> 5;
    int p = pbt*16 + row;
    int g = p & 3, j = p >> 2;
    int wrow = g*512 + j;
    int k = ks*32 + ksub*8 + e;
    float v = (k < 512) ? Wih[(size_t)wrow*512 + k] : Whh[(size_t)wrow*512 + (k-512)];
    Wp[idx] = __float2bfloat16(v);
    if (ks==0 && ksub==0 && e==0) bcp[p] = bih[wrow] + bhh[wrow];
}

// x [B][T][I] f32 -> xbT [T][B][I] bf16
__global__ void xconv(const float* __restrict__ x, __hip_bfloat16* __restrict__ xbT) {
    long idx = (long)blockIdx.x * 256 + threadIdx.x;
    long base = idx * 4;
    int i = (int)(base & (I_ - 1));
    int t = (int)((base >> 8) & (TT - 1));
    int b = (int)(base >> 18);
    const float4 v = *(const float4*)(x + ((long)b * TT + t) * I_ + i);
    __hip_bfloat16* o = xbT + ((long)t * B_ + b) * I_ + i;
    o[0] = __float2bfloat16(v.x); o[1] = __float2bfloat16(v.y);
    o[2] = __float2bfloat16(v.z); o[3] = __float2bfloat16(v.w);
}

// ---------------- shared epilogue (verified R3 math) ----------------
__device__ __forceinline__ void epi_store(const f32x4& acc, const f32x4& bias, float& c,
                                          int jg, int bg, __hip_bfloat16* base) {
    float iv = sigm(acc[0] + bias[0]);
    float fv = sigm(acc[1] + bias[1]);
    float gv = tanh_(acc[2] + bias[2]);
    float ov = sigm(acc[3] + bias[3]);
    c = fv*c + iv*gv;
    float hv = ov * tanh_(c);
    unsigned hb = bf16bits(hv);
    unsigned pr = (unsigned)__shfl_xor((int)hb, 16);
    if ((jg & 1) == 0) {
        u32 val = hb | (pr << 16);
        __hip_atomic_store((u32*)(base + (size_t)bg*H_ + jg), val,
                           __ATOMIC_RELAXED, __HIP_MEMORY_SCOPE_SYSTEM);   // sc0 sc1 write-through
    }
}

#define MFMA(A,Bv,C) __builtin_amdgcn_mfma_f32_16x16x32_bf16((A),(Bv),(C),0,0,0)

// ---------------- cooperative persistent kernel ----------------
// 256 blocks x 512 threads. bid = layer*128 + pt*4 + bt.
// Clique = same bt (32 batch rows, 32 L1 + 32 L2 blocks), private flag set.
// Wave w (0..7): bhalf = w>>2, ppair = w&3. Lane: q = lane>>4, col = lane&15.
// Each lane owns ONE (jg,bg): acc f32x4 = gates (i,f,g,o); c stays in registers.
// h1/h2 triple-buffered (slot t%3). Split flag targets:
//   L1 phase p waits flagL1 >= p && flagL2 >= p-1 ; L2 waits both >= p.

__global__ void __launch_bounds__(512, 2) lstm_coop(
    const __hip_bfloat16* __restrict__ xbT,
    const __hip_bfloat16* __restrict__ W1p, const __hip_bfloat16* __restrict__ W2p,
    const float* __restrict__ bcp1, const float* __restrict__ bcp2,
    __hip_bfloat16* __restrict__ h1b, __hip_bfloat16* __restrict__ h2b,
    int* __restrict__ flags)
{
    const int bid = blockIdx.x, tid = threadIdx.x;
    const int lane = tid & 63, w = tid >> 6;
    const int layer = bid >> 7;
    const int r = bid & 127;
    const int pt = r >> 2, bt = r & 3;
    const int q = lane >> 4, col = lane & 15;
    const int bhalf = w >> 2, ppair = w & 3;
    const int bg = bt*32 + bhalf*16 + col;
    const int jg = pt*16 + ppair*4 + q;
    const int pbt = pt*4 + ppair;
    int* fl = flags + bt*1024;                 // 64 flags x 16-int (64B) stride
    int* myflag = fl + (layer*32 + pt)*16;
    const size_t rdoff = (size_t)bg*H_ + q*8;

    auto pollwait = [&](int tA, int tB){
        if (tid < 64) {
            const int t = (lane < 32) ? tA : tB;
            const int* fp = fl + lane*16;
            while (__ballot(__hip_atomic_load(fp, __ATOMIC_RELAXED,
                                              __HIP_MEMORY_SCOPE_SYSTEM) < t)) {}
            asm volatile("buffer_inv sc0 sc1" ::: "memory");  // drop stale L1/L2 lines
        }
        __syncthreads();
    };
    auto post = [&](int val){
        __syncthreads();                       // all waves' stores drained (vmcnt0)
        if (tid == 0) {
            asm volatile("buffer_wbl2 sc0 sc1\n\ts_waitcnt vmcnt(0)" ::: "memory");
            __hip_atomic_store(myflag, val, __ATOMIC_RELAXED, __HIP_MEMORY_SCOPE_SYSTEM);
        }
    };

    if (layer == 0) {
        bf16x8 wr[24];                                     // 96 VGPRs, resident
        const bf16x8* Wg = reinterpret_cast<const bf16x8*>(W1p);
#pragma unroll
        for (int ks = 0; ks < 24; ++ks)
            wr[ks] = Wg[(pbt*24 + ks)*64 + q*16 + col];
        const f32x4 bias = *reinterpret_cast<const f32x4*>(bcp1 + jg*4);
        float c0 = 0.f;
        // h1 slot pointers: m0=p%3 (write), m2=(p+2)%3 (read); p starts at 0
        __hip_bfloat16* pb0 = h1b;
        __hip_bfloat16* pb1 = h1b + BH;
        __hip_bfloat16* pb2 = h1b + 2*BH;

        bf16x8 xc[8];
        {
            const __hip_bfloat16* xr = xbT + (size_t)bg*I_ + q*8;
#pragma unroll
            for (int s = 0; s < 8; ++s) xc[s] = *reinterpret_cast<const bf16x8*>(xr + s*32);
        }

        for (int p = 0; p < TT; ++p) {
            pollwait(p, p-1);
            const __hip_bfloat16* rd = pb2 + rdoff;        // h1[p-1]
            bf16x8 fA[8], fB[8];
#pragma unroll
            for (int s = 0; s < 8; ++s) fA[s] = *reinterpret_cast<const bf16x8*>(rd + s*32);
#pragma unroll
            for (int s = 0; s < 8; ++s) fB[s] = *reinterpret_cast<const bf16x8*>(rd + (8+s)*32);
            f32x4 acc = {0.f,0.f,0.f,0.f};
#pragma unroll
            for (int s = 0; s < 8; ++s) acc = MFMA(wr[s],    xc[s], acc);
#pragma unroll
            for (int s = 0; s < 8; ++s) acc = MFMA(wr[8+s],  fA[s], acc);
#pragma unroll
            for (int s = 0; s < 8; ++s) acc = MFMA(wr[16+s], fB[s], acc);
            epi_store(acc, bias, c0, jg, bg, pb0);         // h1[p]
            post(p+1);
            if (p + 1 < TT) {                              // x prefetch rides under next poll
                const __hip_bfloat16* xr = xbT + ((size_t)(p+1)*B_ + bg)*I_ + q*8;
#pragma unroll
                for (int s = 0; s < 8; ++s) xc[s] = *reinterpret_cast<const bf16x8*>(xr + s*32);
            }
            __hip_bfloat16* t0 = pb0; pb0 = pb1; pb1 = pb2; pb2 = t0;
        }
    } else {
        bf16x8 wr[32];                                     // 128 VGPRs, resident
        const bf16x8* Wg = reinterpret_cast<const bf16x8*>(W2p);
#pragma unroll
        for (int ks = 0; ks < 32; ++ks)
            wr[ks] = Wg[(pbt*32 + ks)*64 + q*16 + col];
        const f32x4 bias = *reinterpret_cast<const f32x4*>(bcp2 + jg*4);
        float c0 = 0.f;
        // p starts at 1: m0=1,m1=2,m2=0. g_i ~ h1 slots, v_i ~ h2 slots.
        __hip_bfloat16* g0 = h1b + BH;
        __hip_bfloat16* g1 = h1b + 2*BH;
        __hip_bfloat16* g2 = h1b;
        __hip_bfloat16* v0 = h2b + BH;
        __hip_bfloat16* v1 = h2b + 2*BH;
        __hip_bfloat16* v2 = h2b;

        for (int p = 1; p <= TT; ++p) {
            pollwait(p, p);
            const __hip_bfloat16* rd1 = g2 + rdoff;        // h1[p-1]
            const __hip_bfloat16* rd2 = v1 + rdoff;        // h2[p-2]
            bf16x8 fA[8], fB[8];
#pragma unroll
            for (int s = 0; s < 8; ++s) fA[s] = *reinterpret_cast<const bf16x8*>(rd1 + s*32);
#pragma unroll
            for (int s = 0; s < 8; ++s) fB[s] = *reinterpret_cast<const bf16x8*>(rd1 + (8+s)*32);
            f32x4 acc = {0.f,0.f,0.f,0.f};
#pragma unroll
            for (int s = 0; s < 8; ++s) acc = MFMA(wr[s], fA[s], acc);
#pragma unroll
            for (int s = 0; s < 8; ++s) fA[s] = *reinterpret_cast<const bf16x8*>(rd2 + s*32);
#pragma unroll
            for (int s = 0; s < 8; ++s) acc = MFMA(wr[8+s], fB[s], acc);
#pragma unroll
            for (int s = 0; s < 8; ++s) fB[s] = *reinterpret_cast<const bf16x8*>(rd2 + (8+s)*32);
#pragma unroll
            for (int s = 0; s < 8; ++s) acc = MFMA(wr[16+s], fA[s], acc);
#pragma unroll
            for (int s = 0; s < 8; ++s) acc = MFMA(wr[24+s], fB[s], acc);
            epi_store(acc, bias, c0, jg, bg, v2);          // h2[p-1]
            post(p+1);
            __hip_bfloat16* t0 = g0; g0 = g1; g1 = g2; g2 = t0;
            __hip_bfloat16* t1 = v0; v0 = v1; v1 = v2; v2 = t1;
        }
    }
}

// ---------------- per-phase fallback (R3-verbatim, c in global, double-buffer) ----------------
__global__ void __launch_bounds__(256, 1) lstm_step(
    int p,
    const __hip_bfloat16* __restrict__ xbT,
    const __hip_bfloat16* __restrict__ W1p, const __hip_bfloat16* __restrict__ W2p,
    const float* __restrict__ bcp1, const float* __restrict__ bcp2,
    __hip_bfloat16* __restrict__ h1b, __hip_bfloat16* __restrict__ h2b,
    float* __restrict__ cw1, float* __restrict__ cw2)
{
    const int bid = blockIdx.x, tid = threadIdx.x;
    const int lane = tid & 63, w = tid >> 6;
    const int layer = bid >> 7;
    const int r = bid & 127;
    const int pt = r >> 2, bt = r & 3;
    const int q = lane >> 4, col = lane & 15;
    const int bhalf = w >> 1, ppair = w & 1;
    const int bg = bt*32 + bhalf*16 + col;
    const int jg0 = pt*16 + ppair*8 + q;
    const int jg1 = jg0 + 4;

    if (layer == 0) {
        if (p >= TT) return;
        bf16x8 wr[48];
        const bf16x8* Wg = reinterpret_cast<const bf16x8*>(W1p);
#pragma unroll
        for (int a = 0; a < 2; ++a) {
            int pbt = pt*4 + ppair*2 + a;
#pragma unroll
            for (int ks = 0; ks < 24; ++ks)
                wr[a*24 + ks] = Wg[(pbt*24 + ks)*64 + q*16 + col];
        }
        const f32x4 bias0 = *reinterpret_cast<const f32x4*>(bcp1 + jg0*4);
        const f32x4 bias1 = *reinterpret_cast<const f32x4*>(bcp1 + jg1*4);
        float c0 = cw1[(size_t)bg*H_ + jg0];
        float c1 = cw1[(size_t)bg*H_ + jg1];
        const __hip_bfloat16* xr = xbT + ((size_t)p*B_ + bg)*I_ + q*8;
        const __hip_bfloat16* h1r = h1b + ((p-1)&1)*BH + (size_t)bg*H_ + q*8;
        f32x4 acc0 = {0.f,0.f,0.f,0.f}, acc1 = {0.f,0.f,0.f,0.f};
#pragma unroll
        for (int s = 0; s < 8; ++s) {
            bf16x8 xv = *reinterpret_cast<const bf16x8*>(xr + s*32);
            acc0 = MFMA(wr[s],    xv, acc0);
            acc1 = MFMA(wr[24+s], xv, acc1);
        }
#pragma unroll
        for (int kc = 0; kc < 2; ++kc) {
#pragma unroll
            for (int s = 0; s < 8; ++s) {
                bf16x8 bv = *reinterpret_cast<const bf16x8*>(h1r + (kc*8+s)*32);
                acc0 = MFMA(wr[8+kc*8+s],  bv, acc0);
                acc1 = MFMA(wr[32+kc*8+s], bv, acc1);
            }
        }
        __hip_bfloat16* hout = h1b + (p&1)*BH;
        epi_store(acc0, bias0, c0, jg0, bg, hout);
        epi_store(acc1, bias1, c1, jg1, bg, hout);
        cw1[(size_t)bg*H_ + jg0] = c0;
        cw1[(size_t)bg*H_ + jg1] = c1;
    } else {
        if (p < 1) return;
        bf16x8 wr[64];
        const bf16x8* Wg = reinterpret_cast<const bf16x8*>(W2p);
#pragma unroll
        for (int a = 0; a < 2; ++a) {
            int pbt = pt*4 + ppair*2 + a;
#pragma unroll
            for (int ks = 0; ks < 32; ++ks)
                wr[a*32 + ks] = Wg[(pbt*32 + ks)*64 + q*16 + col];
        }
        const f32x4 bias0 = *reinterpret_cast<const f32x4*>(bcp2 + jg0*4);
        const f32x4 bias1 = *reinterpret_cast<const f32x4*>(bcp2 + jg1*4);
        float c0 = cw2[(size_t)bg*H_ + jg0];
        float c1 = cw2[(size_t)bg*H_ + jg1];
        const __hip_bfloat16* h1r = h1b + ((p-1)&1)*BH + (size_t)bg*H_ + q*8;
        const __hip_bfloat16* h2r = h2b + (p&1)*BH     + (size_t)bg*H_ + q*8;
        f32x4 acc0 = {0.f,0.f,0.f,0.f}, acc1 = {0.f,0.f,0.f,0.f};
#pragma unroll
        for (int kc = 0; kc < 2; ++kc) {
#pragma unroll
            for (int s = 0; s < 8; ++s) {
                bf16x8 bv = *reinterpret_cast<const bf16x8*>(h1r + (kc*8+s)*32);
                acc0 = MFMA(wr[kc*8+s],    bv, acc0);
                acc1 = MFMA(wr[32+kc*8+s], bv, acc1);
            }
        }
#pragma unroll
        for (int kc = 0; kc < 2; ++kc) {
#pragma unroll
            for (int s = 0; s < 8; ++s) {
                bf16x8 bv = *reinterpret_cast<const bf16x8*>(h2r + (kc*8+s)*32);
                acc0 = MFMA(wr[16+kc*8+s], bv, acc0);
                acc1 = MFMA(wr[48+kc*8+s], bv, acc1);
            }
        }
        __hip_bfloat16* hout = h2b + ((p-1)&1)*BH;
        epi_store(acc0, bias0, c0, jg0, bg, hout);
        epi_store(acc1, bias1, c1, jg1, bg, hout);
        cw2[(size_t)bg*H_ + jg0] = c0;
        cw2[(size_t)bg*H_ + jg1] = c1;
    }
}

// out[b][c] = h2[b] . Wout[c] + bout[c]
__global__ void proj_kernel(const __hip_bfloat16* __restrict__ h2,
                            const float* __restrict__ Wout, const float* __restrict__ bout,
                            float* __restrict__ out) {
    int b = blockIdx.x, lane = threadIdx.x; // 64 threads
    const bf16x8 h8 = *reinterpret_cast<const bf16x8*>(h2 + b * 512 + lane * 8);
    float hv[8];
#pragma unroll
    for (int e = 0; e < 8; ++e) hv[e] = (float)h8[e];
    for (int c = 0; c < 10; ++c) {
        const float4 w0 = *(const float4*)(Wout + c * 512 + lane * 8);
        const float4 w1 = *(const float4*)(Wout + c * 512 + lane * 8 + 4);
        float s = hv[0] * w0.x + hv[1] * w0.y + hv[2] * w0.z + hv[3] * w0.w +
                  hv[4] * w1.x + hv[5] * w1.y + hv[6] * w1.z + hv[7] * w1.w;
#pragma unroll
        for (int off = 32; off > 0; off >>= 1) s += __shfl_down(s, off);
        if (lane == 0) out[b * 10 + c] = s + bout[c];
    }
}

extern "C" void kernel_launch(void* const* d_in, const int* in_sizes, int n_in,
                              void* d_out, int out_size, void* d_ws, size_t ws_size,
                              hipStream_t stream) {
    const float* x    = (const float*)d_in[0];
    const float* Wih1 = (const float*)d_in[1];
    const float* Whh1 = (const float*)d_in[2];
    const float* bih1 = (const float*)d_in[3];
    const float* bhh1 = (const float*)d_in[4];
    const float* Wih2 = (const float*)d_in[5];
    const float* Whh2 = (const float*)d_in[6];
    const float* bih2 = (const float*)d_in[7];
    const float* bhh2 = (const float*)d_in[8];
    const float* Wout = (const float*)d_in[9];
    const float* bout = (const float*)d_in[10];
    float* out = (float*)d_out;

    char* ws = (char*)d_ws;
    size_t off = 0;
    auto alloc = [&](size_t bytes) -> void* {
        void* pp = ws + off;
        off += (bytes + 255) & ~(size_t)255;
        return pp;
    };
    __hip_bfloat16* W1p = (__hip_bfloat16*)alloc((size_t)128*24*512*2);
    __hip_bfloat16* W2p = (__hip_bfloat16*)alloc((size_t)128*32*512*2);
    float* bcp1 = (float*)alloc(2048*4);
    float* bcp2 = (float*)alloc(2048*4);
    __hip_bfloat16* h1b = (__hip_bfloat16*)alloc((size_t)3*BH*2);     // 384 KB (3 slots)
    __hip_bfloat16* h2b = (__hip_bfloat16*)alloc((size_t)3*BH*2);     // 384 KB
    float* cw1 = (float*)alloc((size_t)BH*4);                          // fallback only
    float* cw2 = (float*)alloc((size_t)BH*4);
    int* flags = (int*)alloc(4096*4);                                  // 4 cliques x 64 flags x 64B
    __hip_bfloat16* xbT = (__hip_bfloat16*)alloc((size_t)TT*B_*I_*2);  // 64 MB
    if (off > ws_size) return;

    // zero h slots + c + flags (contiguous region starting at h1b)
    hipMemsetAsync(h1b, 0, (size_t)6*BH*2 + (size_t)2*BH*4 + 4096*4, stream);

    pack_w1<<<(128*24*512)/256, 256, 0, stream>>>(Wih1, Whh1, bih1, bhh1, W1p, bcp1);
    pack_w2<<<(128*32*512)/256, 256, 0, stream>>>(Wih2, Whh2, bih2, bhh2, W2p, bcp2);
    xconv<<<((long)TT*B_*I_/4)/256, 256, 0, stream>>>(x, xbT);

    int dev = 0;
    hipGetDevice(&dev);
    int nCU = 0;
    hipDeviceGetAttribute(&nCU, hipDeviceAttributeMultiprocessorCount, dev);
    int perCU = 0;
    hipOccupancyMaxActiveBlocksPerMultiprocessor(&perCU, lstm_coop, 512, 0);
    const bool useCoop = ((long)perCU * nCU >= 256);

    const __hip_bfloat16* xbT_ = xbT;
    const __hip_bfloat16* W1p_ = W1p;
    const __hip_bfloat16* W2p_ = W2p;
    const float* bcp1_ = bcp1;
    const float* bcp2_ = bcp2;
    __hip_bfloat16* h1b_ = h1b;
    __hip_bfloat16* h2b_ = h2b;
    int* flags_ = flags;

    if (useCoop) {
        void* args[] = {&xbT_, &W1p_, &W2p_, &bcp1_, &bcp2_, &h1b_, &h2b_, &flags_};
        hipLaunchCooperativeKernel((void*)lstm_coop, dim3(256), dim3(512), args, 0, stream);
        // h2[TT-1] in slot (TT-1)%3 == 0
        proj_kernel<<<B_, 64, 0, stream>>>(h2b, Wout, bout, out);
    } else {
        for (int p = 0; p <= TT; ++p)
            lstm_step<<<256, 256, 0, stream>>>(p, xbT, W1p, W2p, bcp1, bcp2,
                                               h1b, h2b, cw1, cw2);
        // fallback double-buffers: h2[TT-1] in buffer (TT-1)&1 == 1
        proj_kernel<<<B_, 64, 0, stream>>>(h2b + BH, Wout, bout, out);
    }
}